// Round 2
// baseline (588.695 us; speedup 1.0000x reference)
//
#include <hip/hip_runtime.h>
#include <hip/hip_bf16.h>

#define DIM       4096
#define NHEADS    32
#define NKV       8
#define HD        128
#define NREP      4
#define CACHELEN  2080
#define QKVN      6144   /* 4096 q + 1024 k + 1024 v */
#define BSZ       32
#define SP0       2048
#define SP1       1024
#define KCHUNK    512

typedef unsigned short u16;
typedef unsigned int   u32;
typedef __bf16 bf16x8 __attribute__((ext_vector_type(8)));
typedef float  f32x4  __attribute__((ext_vector_type(4)));

static __device__ __forceinline__ bf16x8 pack8(float4 lo, float4 hi) {
    bf16x8 r;
    r[0] = (__bf16)lo.x; r[1] = (__bf16)lo.y; r[2] = (__bf16)lo.z; r[3] = (__bf16)lo.w;
    r[4] = (__bf16)hi.x; r[5] = (__bf16)hi.y; r[6] = (__bf16)hi.z; r[7] = (__bf16)hi.w;
    return r;
}

// ---------------------------------------------------------------------------
// K1: QKV projection. out[m][n] = sum_k x[m][k] * W[n][k], W in {wq,wk,wv}.
// All inputs fp32; converted to bf16 in-register for MFMA 16x16x32.
// A frag: lane l -> x[l&15][k + (l>>4)*8 + j]   (8 consecutive elems)
// B frag: lane l -> W[n0+(l&15)][k + (l>>4)*8 + j]
// C/D:    col = lane&15, row = (lane>>4)*4 + reg   (m89-verified layout)
// grid.x: n-tiles/4 (4 waves per block), grid.y: K splits (atomic f32 accum)
// ---------------------------------------------------------------------------
__global__ __launch_bounds__(256) void qkv_gemm(
    const float* __restrict__ x, const float* __restrict__ wq,
    const float* __restrict__ wk, const float* __restrict__ wv,
    float* __restrict__ qkv_acc)
{
    const int lane = threadIdx.x & 63;
    const int w    = threadIdx.x >> 6;
    const int n0   = (blockIdx.x * 4 + w) * 16;
    const float* W; int nr;
    if (n0 < 4096)      { W = wq; nr = n0; }
    else if (n0 < 5120) { W = wk; nr = n0 - 4096; }
    else                { W = wv; nr = n0 - 5120; }
    const int c16  = lane & 15;
    const int quad = lane >> 4;
    const int k0   = blockIdx.y * KCHUNK;
    const float* ap0 = x + (size_t)c16 * DIM + k0 + quad * 8;
    const float* ap1 = ap0 + 16 * DIM;
    const float* bp  = W + (size_t)(nr + c16) * DIM + k0 + quad * 8;
    f32x4 acc0 = {0.f,0.f,0.f,0.f}, acc1 = {0.f,0.f,0.f,0.f};
#pragma unroll 4
    for (int kk = 0; kk < KCHUNK; kk += 32) {
        bf16x8 a0 = pack8(*(const float4*)(ap0 + kk), *(const float4*)(ap0 + kk + 4));
        bf16x8 a1 = pack8(*(const float4*)(ap1 + kk), *(const float4*)(ap1 + kk + 4));
        bf16x8 b  = pack8(*(const float4*)(bp  + kk), *(const float4*)(bp  + kk + 4));
        acc0 = __builtin_amdgcn_mfma_f32_16x16x32_bf16(a0, b, acc0, 0, 0, 0);
        acc1 = __builtin_amdgcn_mfma_f32_16x16x32_bf16(a1, b, acc1, 0, 0, 0);
    }
#pragma unroll
    for (int r = 0; r < 4; ++r) {
        int m = quad * 4 + r;
        atomicAdd(&qkv_acc[(size_t)m * QKVN + n0 + c16], acc0[r]);
        atomicAdd(&qkv_acc[(size_t)(m + 16) * QKVN + n0 + c16], acc1[r]);
    }
}

// ---------------------------------------------------------------------------
// K2: decode attention, one block per (batch, kv-head). RoPE applied inline.
// Lane partition: ch = lane&15 covers dims [ch*8, ch*8+8),
// quad = lane>>4 selects the row within a 4-row coalesced wave load
// (16 lanes x 32B = 512B = one full K row, contiguous).
// Per-lane online softmax over its rows; merge: shfl quads -> LDS waves.
// All fp32.
// ---------------------------------------------------------------------------
__global__ __launch_bounds__(256) void attn_decode(
    const float* __restrict__ qkv,
    const float* __restrict__ ck0, const float* __restrict__ cv0,
    const float* __restrict__ ck1, const float* __restrict__ cv1,
    const float* __restrict__ fcos, const float* __restrict__ fsin,
    float* __restrict__ attn)
{
    const int tid  = threadIdx.x;
    const int lane = tid & 63;
    const int w    = tid >> 6;
    const int quad = lane >> 4;
    const int ch   = lane & 15;
    const int db   = ch * 8;

    const int b = blockIdx.x >> 3;
    const int g = blockIdx.x & 7;

    int sp; const float *CK, *CV;
    if (b < 16) { sp = SP0; size_t off = (size_t)b * CACHELEN * NKV * HD; CK = ck0 + off; CV = cv0 + off; }
    else        { sp = SP1; size_t off = (size_t)(b - 16) * CACHELEN * NKV * HD; CK = ck1 + off; CV = cv1 + off; }

    // RoPE cos/sin for this lane's 4 pairs at position sp
    float cs[4], sn[4];
#pragma unroll
    for (int i = 0; i < 4; ++i) {
        int fi = sp * (HD / 2) + ch * 4 + i;
        cs[i] = fcos[fi];
        sn[i] = fsin[fi];
    }
    const float rs = 0.08838834764831845f; // 1/sqrt(128)

    // q for the 4 heads of this group: rope + fold in 1/sqrt(d)
    float qv[4][8];
#pragma unroll
    for (int h = 0; h < 4; ++h) {
        const float* qp = qkv + (size_t)b * QKVN + (g * 4 + h) * HD + db;
        float t[8];
#pragma unroll
        for (int j = 0; j < 8; ++j) t[j] = qp[j];
#pragma unroll
        for (int i = 0; i < 4; ++i) {
            float e = t[2 * i], o = t[2 * i + 1];
            qv[h][2 * i]     = (e * cs[i] - o * sn[i]) * rs;
            qv[h][2 * i + 1] = (e * sn[i] + o * cs[i]) * rs;
        }
    }
    // new-token k (roped) and v
    float kn[8], vn[8];
    {
        const float* kp = qkv + (size_t)b * QKVN + 4096 + g * HD + db;
        const float* vp = qkv + (size_t)b * QKVN + 5120 + g * HD + db;
        float t[8];
#pragma unroll
        for (int j = 0; j < 8; ++j) t[j] = kp[j];
#pragma unroll
        for (int i = 0; i < 4; ++i) {
            float e = t[2 * i], o = t[2 * i + 1];
            kn[2 * i]     = e * cs[i] - o * sn[i];
            kn[2 * i + 1] = e * sn[i] + o * cs[i];
        }
#pragma unroll
        for (int j = 0; j < 8; ++j) vn[j] = vp[j];
    }

    float m_[4] = {-INFINITY, -INFINITY, -INFINITY, -INFINITY};
    float l_[4] = {0.f, 0.f, 0.f, 0.f};
    float acc[4][8];
#pragma unroll
    for (int h = 0; h < 4; ++h)
#pragma unroll
        for (int j = 0; j < 8; ++j) acc[h][j] = 0.f;

    const size_t rstride = NKV * HD; // 1024 floats per cache row
    const float* kbase = CK + g * HD + db;
    const float* vbase = CV + g * HD + db;

    auto process = [&](const float* kf, const float* vf) {
        float d0 = 0.f, d1 = 0.f, d2 = 0.f, d3 = 0.f;
#pragma unroll
        for (int j = 0; j < 8; ++j) {
            d0 = fmaf(qv[0][j], kf[j], d0);
            d1 = fmaf(qv[1][j], kf[j], d1);
            d2 = fmaf(qv[2][j], kf[j], d2);
            d3 = fmaf(qv[3][j], kf[j], d3);
        }
#pragma unroll
        for (int off = 1; off < 16; off <<= 1) {
            d0 += __shfl_xor(d0, off);
            d1 += __shfl_xor(d1, off);
            d2 += __shfl_xor(d2, off);
            d3 += __shfl_xor(d3, off);
        }
        float sc[4] = {d0, d1, d2, d3};
#pragma unroll
        for (int h = 0; h < 4; ++h) {
            float mn = fmaxf(m_[h], sc[h]);
            float sl = __expf(m_[h] - mn);
            float p  = __expf(sc[h] - mn);
            l_[h] = l_[h] * sl + p;
#pragma unroll
            for (int j = 0; j < 8; ++j)
                acc[h][j] = fmaf(acc[h][j], sl, p * vf[j]);
            m_[h] = mn;
        }
    };

    const int iters = sp >> 5; // 32 rows per block-iter (4 waves x 8 rows)
    for (int it = 0; it < iters; ++it) {
        int r0 = it * 32 + w * 8 + quad;
        const float* kp0 = kbase + (size_t)r0 * rstride;
        const float* vp0 = vbase + (size_t)r0 * rstride;
        float K0[8], V0[8], K1[8], V1[8];
        *(float4*)(K0)     = *(const float4*)kp0;
        *(float4*)(K0 + 4) = *(const float4*)(kp0 + 4);
        *(float4*)(V0)     = *(const float4*)vp0;
        *(float4*)(V0 + 4) = *(const float4*)(vp0 + 4);
        *(float4*)(K1)     = *(const float4*)(kp0 + 4 * rstride);
        *(float4*)(K1 + 4) = *(const float4*)(kp0 + 4 * rstride + 4);
        *(float4*)(V1)     = *(const float4*)(vp0 + 4 * rstride);
        *(float4*)(V1 + 4) = *(const float4*)(vp0 + 4 * rstride + 4);
        process(K0, V0);
        process(K1, V1);
    }

    // new token (position sp): all lanes compute the score, wave0/quad0 applies
    {
        float d0 = 0.f, d1 = 0.f, d2 = 0.f, d3 = 0.f;
#pragma unroll
        for (int j = 0; j < 8; ++j) {
            d0 = fmaf(qv[0][j], kn[j], d0);
            d1 = fmaf(qv[1][j], kn[j], d1);
            d2 = fmaf(qv[2][j], kn[j], d2);
            d3 = fmaf(qv[3][j], kn[j], d3);
        }
#pragma unroll
        for (int off = 1; off < 16; off <<= 1) {
            d0 += __shfl_xor(d0, off);
            d1 += __shfl_xor(d1, off);
            d2 += __shfl_xor(d2, off);
            d3 += __shfl_xor(d3, off);
        }
        if (w == 0 && quad == 0) {
            float sc[4] = {d0, d1, d2, d3};
#pragma unroll
            for (int h = 0; h < 4; ++h) {
                float mn = fmaxf(m_[h], sc[h]);
                float sl = __expf(m_[h] - mn);
                float p  = __expf(sc[h] - mn);
                l_[h] = l_[h] * sl + p;
#pragma unroll
                for (int j = 0; j < 8; ++j)
                    acc[h][j] = fmaf(acc[h][j], sl, p * vn[j]);
                m_[h] = mn;
            }
        }
    }

    // merge the 4 quads within each wave (lanes l, l^16, l^32 share ch)
#pragma unroll
    for (int off = 16; off <= 32; off <<= 1) {
#pragma unroll
        for (int h = 0; h < 4; ++h) {
            float mo = __shfl_xor(m_[h], off);
            float lo = __shfl_xor(l_[h], off);
            float ao[8];
#pragma unroll
            for (int j = 0; j < 8; ++j) ao[j] = __shfl_xor(acc[h][j], off);
            float mn = fmaxf(m_[h], mo);
            float s1 = __expf(m_[h] - mn);
            float s2 = __expf(mo - mn);
            l_[h] = l_[h] * s1 + lo * s2;
#pragma unroll
            for (int j = 0; j < 8; ++j) acc[h][j] = acc[h][j] * s1 + ao[j] * s2;
            m_[h] = mn;
        }
    }

    // cross-wave merge via LDS
    __shared__ float ls_m[4][4][16];
    __shared__ float ls_l[4][4][16];
    __shared__ float ls_a[4][4][16][8];
    if (quad == 0) {
#pragma unroll
        for (int h = 0; h < 4; ++h) {
            ls_m[w][h][ch] = m_[h];
            ls_l[w][h][ch] = l_[h];
#pragma unroll
            for (int j = 0; j < 8; ++j) ls_a[w][h][ch][j] = acc[h][j];
        }
    }
    __syncthreads();
    if (tid < 64) {
        int h = tid >> 4, c = tid & 15;
        float mm = -INFINITY, ll = 0.f, ac[8] = {0.f,0.f,0.f,0.f,0.f,0.f,0.f,0.f};
#pragma unroll
        for (int w2 = 0; w2 < 4; ++w2) {
            float m2 = ls_m[w2][h][c], l2 = ls_l[w2][h][c];
            float mn = fmaxf(mm, m2);
            float s1 = __expf(mm - mn), s2 = __expf(m2 - mn);
            ll = ll * s1 + l2 * s2;
#pragma unroll
            for (int j = 0; j < 8; ++j) ac[j] = ac[j] * s1 + ls_a[w2][h][c][j] * s2;
            mm = mn;
        }
        float inv = 1.f / ll;
        float* op = attn + (size_t)b * DIM + (g * 4 + h) * HD + c * 8;
        float4 o0, o1;
        o0.x = ac[0] * inv; o0.y = ac[1] * inv; o0.z = ac[2] * inv; o0.w = ac[3] * inv;
        o1.x = ac[4] * inv; o1.y = ac[5] * inv; o1.z = ac[6] * inv; o1.w = ac[7] * inv;
        *(float4*)op       = o0;
        *(float4*)(op + 4) = o1;
    }
}

// ---------------------------------------------------------------------------
// K3: output projection. out[m][n] = sum_k attn[m][k] * wo[n][k]
// fp32 inputs converted to bf16 frags; atomics straight into d_out (f32).
// ---------------------------------------------------------------------------
__global__ __launch_bounds__(256) void out_gemm(
    const float* __restrict__ A, const float* __restrict__ wo,
    float* __restrict__ out)
{
    const int lane = threadIdx.x & 63;
    const int w    = threadIdx.x >> 6;
    const int n0   = (blockIdx.x * 4 + w) * 16;
    const int c16  = lane & 15;
    const int quad = lane >> 4;
    const int k0   = blockIdx.y * KCHUNK;
    const float* ap0 = A + (size_t)c16 * DIM + k0 + quad * 8;
    const float* ap1 = ap0 + 16 * DIM;
    const float* bp  = wo + (size_t)(n0 + c16) * DIM + k0 + quad * 8;
    f32x4 acc0 = {0.f,0.f,0.f,0.f}, acc1 = {0.f,0.f,0.f,0.f};
#pragma unroll 4
    for (int kk = 0; kk < KCHUNK; kk += 32) {
        bf16x8 a0 = pack8(*(const float4*)(ap0 + kk), *(const float4*)(ap0 + kk + 4));
        bf16x8 a1 = pack8(*(const float4*)(ap1 + kk), *(const float4*)(ap1 + kk + 4));
        bf16x8 b  = pack8(*(const float4*)(bp  + kk), *(const float4*)(bp  + kk + 4));
        acc0 = __builtin_amdgcn_mfma_f32_16x16x32_bf16(a0, b, acc0, 0, 0, 0);
        acc1 = __builtin_amdgcn_mfma_f32_16x16x32_bf16(a1, b, acc1, 0, 0, 0);
    }
#pragma unroll
    for (int r = 0; r < 4; ++r) {
        int m = quad * 4 + r;
        atomicAdd(&out[(size_t)m * DIM + n0 + c16], acc0[r]);
        atomicAdd(&out[(size_t)(m + 16) * DIM + n0 + c16], acc1[r]);
    }
}

extern "C" void kernel_launch(void* const* d_in, const int* in_sizes, int n_in,
                              void* d_out, int out_size, void* d_ws, size_t ws_size,
                              hipStream_t stream)
{
    const float* x   = (const float*)d_in[0];
    const float* wq  = (const float*)d_in[1];
    const float* wk  = (const float*)d_in[2];
    const float* wv  = (const float*)d_in[3];
    const float* wo  = (const float*)d_in[4];
    const float* ck0 = (const float*)d_in[5];
    const float* cv0 = (const float*)d_in[6];
    const float* ck1 = (const float*)d_in[7];
    const float* cv1 = (const float*)d_in[8];
    const float* fc  = (const float*)d_in[9];
    const float* fs  = (const float*)d_in[10];

    float* qkv_acc = (float*)d_ws;                    // 32*6144 f32
    float* attn    = qkv_acc + BSZ * QKVN;            // 32*4096 f32
    float* out     = (float*)d_out;                   // 32*4096 f32

    // zero the f32 atomic accumulators (ws/out are poisoned before each launch)
    hipMemsetAsync(qkv_acc, 0, (size_t)(BSZ * QKVN) * sizeof(float), stream);
    hipMemsetAsync(out, 0, (size_t)(BSZ * DIM) * sizeof(float), stream);

    qkv_gemm<<<dim3(QKVN / 64, DIM / KCHUNK), 256, 0, stream>>>(x, wq, wk, wv, qkv_acc);
    attn_decode<<<dim3(BSZ * NKV), 256, 0, stream>>>(qkv_acc, ck0, cv0, ck1, cv1, fc, fs, attn);
    out_gemm<<<dim3(DIM / 64, DIM / KCHUNK), 256, 0, stream>>>(attn, wo, out);
}